// Round 21
// baseline (120.208 us; speedup 1.0000x reference)
//
#include <hip/hip_runtime.h>
#include <hip/hip_bf16.h>
#include <math.h>

#define NN 50000
#define FIN 48
#define HC 64   // 8 heads x 8 ch
#define NHEAD 8
#define NCH 8
#define NCLS 2
#define NEG 0.2f
#define LOG2E 1.44269504f

#define NPB 98                         // nodes per bucket
#define NBKT 512                       // buckets (NPB*NBKT >= NN)
#define CAP 4096                       // csr capacity per bucket
#define BCHUNK 4096                    // edges per binning workgroup
#define SLOT 32                        // slots per (block,bucket): Poisson mean 8, +8.5 sigma

// ---------------- fused: edge binning (blocks 0..nbin-1)  ||  layer-1 GEMM (rest) ----------------
// binning: DETERMINISTIC slots — pairs[(k*nbin+b)*SLOT+pos], counts cnt[b*NBKT+k].
// Handles ONLY the e random edges (self-loops are injected analytically in bucket_csr —
// they're sequential and would overflow the per-block slots). No global atomics anywhere.

__global__ __launch_bounds__(256, 4)
void k_bin_h1(const int* __restrict__ ei, int* __restrict__ cnt,
              int* __restrict__ pairs, int e, int nbin,
              const float* __restrict__ x, const float* __restrict__ W1,
              const float* __restrict__ as1, const float* __restrict__ ad1,
              __hip_bfloat16* __restrict__ h1b, __hip_bfloat16* __restrict__ es1b,
              float* __restrict__ ed1, int n) {
    __shared__ int hist[NBKT];
    __shared__ float xs[16][FIN];
    int t = threadIdx.x;
    if ((int)blockIdx.x < nbin) {
        int bid = blockIdx.x;
        hist[t] = 0; hist[t + 256] = 0;
        __syncthreads();
        int base = bid * BCHUNK;
        int end = min(base + BCHUNK, e);
        int pk[16];   // payload (dloc<<16 | src)
        int bp[16];   // (bucket<<16 | local pos), -1 = invalid
        #pragma unroll
        for (int k = 0; k < 16; ++k) {
            int i = base + t + k * 256;
            if (i < end) {
                int s = ei[i], d = ei[e + i];
                int b = d / NPB;
                int p = atomicAdd(&hist[b], 1);
                pk[k] = ((d - b * NPB) << 16) | s;
                bp[k] = (b << 16) | p;
            } else bp[k] = -1;
        }
        __syncthreads();
        // coalesced per-block counts
        cnt[bid * NBKT + t]       = hist[t];
        cnt[bid * NBKT + t + 256] = hist[t + 256];
        // deterministic slot writes (no reservation needed)
        #pragma unroll
        for (int k = 0; k < 16; ++k) {
            if (bp[k] >= 0) {
                int b = bp[k] >> 16;
                int p = bp[k] & 0xFFFF;
                if (p < SLOT) pairs[(b * nbin + bid) * SLOT + p] = pk[k];
            }
        }
    } else {
        // ---- layer-1: register-tiled GEMM (unchanged) ----
        int j = t & 63, row = t >> 6;
        float wreg[FIN];
        #pragma unroll
        for (int k = 0; k < FIN; ++k) wreg[k] = W1[k * HC + j];
        float asl = as1[j] * LOG2E, adl = ad1[j] * LOG2E;
        int hh = j >> 3, c = j & 7;
        int ngroups = (n + 15) >> 4;
        int GB = gridDim.x - nbin;
        for (int g = blockIdx.x - nbin; g < ngroups; g += GB) {
            int nb = g * 16;
            __syncthreads();
            for (int i = t; i < 16 * FIN; i += 256) {
                int l = i / FIN, k = i % FIN;
                int nd = nb + l;
                xs[l][k] = (nd < n) ? x[nd * FIN + k] : 0.f;
            }
            __syncthreads();
            #pragma unroll
            for (int m = 0; m < 4; ++m) {
                int l = (row << 2) + m;
                float acc = 0.f;
                #pragma unroll
                for (int k = 0; k < FIN; ++k) acc += xs[l][k] * wreg[k];
                int nd = nb + l;
                if (nd < n) h1b[nd * HC + j] = __float2bfloat16(acc);
                float es = acc * asl, ed = acc * adl;
                es += __shfl_xor(es, 1, 64); es += __shfl_xor(es, 2, 64); es += __shfl_xor(es, 4, 64);
                ed += __shfl_xor(ed, 1, 64); ed += __shfl_xor(ed, 2, 64); ed += __shfl_xor(ed, 4, 64);
                if (nd < n) {
                    if (c == 0) es1b[nd * NHEAD + hh] = __float2bfloat16(es);
                    if (c == 1) ed1[nd * NHEAD + hh] = ed;
                }
            }
        }
    }
}

// ---------------- per-bucket CSR from deterministic slots + analytic self-loops ----------------
// block k: stream its bucket's nbin slot-runs (contiguous), masked by cnt;
// self-loop of node lo+t injected via +1 in the degree histogram and a direct write.

__global__ void k_bucket_csr(const int* __restrict__ pairs, const int* __restrict__ cnt,
                             int* __restrict__ rowptr, int* __restrict__ degv,
                             int* __restrict__ csr, int n, int nbin) {
    __shared__ int cnts[512];
    __shared__ int hist[256];
    int k = blockIdx.x, t = threadIdx.x;
    int lo = k * NPB;
    int nn = min(NPB, n - lo);
    if (nn <= 0) return;
    for (int b = t; b < nbin; b += 256) cnts[b] = cnt[b * NBKT + k];
    hist[t] = (t < nn) ? 1 : 0;              // +1 self-loop per node
    __syncthreads();
    int rbase = k * nbin * SLOT;
    int total_slots = nbin * SLOT;
    // pass 1: per-dst degree histogram over valid slots
    for (int i = t; i < total_slots; i += 256) {
        if ((i & (SLOT - 1)) < cnts[i >> 5]) {
            atomicAdd(&hist[pairs[rbase + i] >> 16], 1);
        }
    }
    __syncthreads();
    int v = hist[t];
    for (int off = 1; off < 256; off <<= 1) {           // inclusive scan
        int y = (t >= off) ? hist[t - off] : 0;
        __syncthreads();
        hist[t] += y;
        __syncthreads();
    }
    int excl = hist[t] - v;
    int base = k * CAP;
    if (t < nn) { rowptr[lo + t] = base + excl; degv[lo + t] = v; }
    __syncthreads();
    hist[t] = excl;                                      // exclusive offsets as cursors
    __syncthreads();
    if (t < nn) {                                        // inject self-loop
        csr[base + excl] = lo + t;
        hist[t] = excl + 1;
    }
    __syncthreads();
    // pass 2: re-read (L2-hot) + scatter within bucket
    for (int i = t; i < total_slots; i += 256) {
        if ((i & (SLOT - 1)) < cnts[i >> 5]) {
            int p = pairs[rbase + i];
            int pos = atomicAdd(&hist[p >> 16], 1);
            csr[base + pos] = p & 0xFFFF;
        }
    }
}

// ---------------- Layer 1 aggregation + fused layer-2 linear ----------------
// wave per dst node; csr row preloaded into rv register; no load->address deps in loop.

__global__ void k_agg1(const __hip_bfloat16* __restrict__ h1b, const __hip_bfloat16* __restrict__ es1b,
                       const float* __restrict__ ed1, const int* __restrict__ rowptr,
                       const int* __restrict__ degv, const int* __restrict__ csr,
                       const float* __restrict__ b1,
                       const float* __restrict__ W2, const float* __restrict__ as2,
                       const float* __restrict__ ad2, float4* __restrict__ node2, int n) {
    int wid = (blockIdx.x * blockDim.x + threadIdx.x) >> 6;
    if (wid >= n) return;
    int lane = threadIdx.x & 63;
    int j  = lane >> 3;                      // weight: edge slot (0..7)
    int hw = lane & 7;                       // weight: head
    int e4 = lane >> 4;                      // accum: edge sub-slot (0..3)
    int r  = lane & 15;
    int ha = r >> 1;                         // accum: head
    int ch0 = (ha << 3) + ((r & 1) << 2);    // first of this lane's 4 channels
    int wbase = (e4 << 3) + ha;              // lane with w(edge e4, head ha); +32 -> edge e4+4
    int start = rowptr[wid];
    int cnt = degv[wid];
    float edv = ed1[wid * NHEAD + hw];
    float sumw = 0.f;
    float a0 = 0.f, a1 = 0.f, a2 = 0.f, a3 = 0.f;
    int nbatch = cnt >> 3;

    // preload first 64 src ids of the row (cnt >= 1 always: self-loop)
    int rv = csr[start + min(lane, cnt - 1)];

    int sl; float ev; uint2 va, vb;
    if (nbatch > 0) {
        sl = __shfl(rv, j, 64);
        ev = __bfloat162float(es1b[sl * NHEAD + hw]);
        int su0 = __shfl(sl, e4 << 3, 64);
        int su1 = __shfl(sl, (4 + e4) << 3, 64);
        va = *(const uint2*)(h1b + su0 * HC + ch0);
        vb = *(const uint2*)(h1b + su1 * HC + ch0);
        for (int b = 1; b < nbatch; ++b) {
            int sl_n;
            if (b < 8) sl_n = __shfl(rv, (b << 3) + j, 64);   // register-sourced
            else       sl_n = csr[start + (b << 3) + j];      // deg>64: rare fallback
            float ev_n = __bfloat162float(es1b[sl_n * NHEAD + hw]);
            int su0n = __shfl(sl_n, e4 << 3, 64);
            int su1n = __shfl(sl_n, (4 + e4) << 3, 64);
            uint2 va_n = *(const uint2*)(h1b + su0n * HC + ch0);
            uint2 vb_n = *(const uint2*)(h1b + su1n * HC + ch0);
            // consume previous batch
            float tt = ev + edv;
            tt = fmaxf(tt, NEG * tt);
            float w = exp2f(tt);
            sumw += w;
            float wj0 = __shfl(w, wbase, 64);
            float wj1 = __shfl(w, wbase + 32, 64);
            a0 += wj0 * __uint_as_float(va.x << 16);
            a1 += wj0 * __uint_as_float(va.x & 0xffff0000u);
            a2 += wj0 * __uint_as_float(va.y << 16);
            a3 += wj0 * __uint_as_float(va.y & 0xffff0000u);
            a0 += wj1 * __uint_as_float(vb.x << 16);
            a1 += wj1 * __uint_as_float(vb.x & 0xffff0000u);
            a2 += wj1 * __uint_as_float(vb.y << 16);
            a3 += wj1 * __uint_as_float(vb.y & 0xffff0000u);
            sl = sl_n; ev = ev_n; va = va_n; vb = vb_n;
        }
        float tt = ev + edv;
        tt = fmaxf(tt, NEG * tt);
        float w = exp2f(tt);
        sumw += w;
        float wj0 = __shfl(w, wbase, 64);
        float wj1 = __shfl(w, wbase + 32, 64);
        a0 += wj0 * __uint_as_float(va.x << 16);
        a1 += wj0 * __uint_as_float(va.x & 0xffff0000u);
        a2 += wj0 * __uint_as_float(va.y << 16);
        a3 += wj0 * __uint_as_float(va.y & 0xffff0000u);
        a0 += wj1 * __uint_as_float(vb.x << 16);
        a1 += wj1 * __uint_as_float(vb.x & 0xffff0000u);
        a2 += wj1 * __uint_as_float(vb.y << 16);
        a3 += wj1 * __uint_as_float(vb.y & 0xffff0000u);
    }
    int i = nbatch << 3;
    if (i < cnt) {                            // tail batch (clamped)
        int idx = min(i + j, cnt - 1);
        int slt = (cnt <= 64) ? __shfl(rv, idx, 64) : csr[start + idx];
        float evt = __bfloat162float(es1b[slt * NHEAD + hw]) + edv;
        evt = fmaxf(evt, NEG * evt);
        float w = (i + j < cnt) ? exp2f(evt) : 0.f;
        sumw += w;
        #pragma unroll
        for (int it = 0; it < 2; ++it) {
            int su   = __shfl(slt, ((it << 2) + e4) << 3, 64);
            float wj = __shfl(w, wbase + (it << 5), 64);
            uint2 v = *(const uint2*)(h1b + su * HC + ch0);
            a0 += wj * __uint_as_float(v.x << 16);
            a1 += wj * __uint_as_float(v.x & 0xffff0000u);
            a2 += wj * __uint_as_float(v.y << 16);
            a3 += wj * __uint_as_float(v.y & 0xffff0000u);
        }
    }
    // denominator: sum over edge slots j (lane stride 8) for fixed head hw
    sumw += __shfl_xor(sumw, 8, 64);
    sumw += __shfl_xor(sumw, 16, 64);
    sumw += __shfl_xor(sumw, 32, 64);
    // accumulator: sum the 4 edge sub-groups (lanes with same r)
    a0 += __shfl_xor(a0, 16, 64); a0 += __shfl_xor(a0, 32, 64);
    a1 += __shfl_xor(a1, 16, 64); a1 += __shfl_xor(a1, 32, 64);
    a2 += __shfl_xor(a2, 16, 64); a2 += __shfl_xor(a2, 32, 64);
    a3 += __shfl_xor(a3, 16, 64); a3 += __shfl_xor(a3, 32, 64);
    float sden = __shfl(sumw, ha, 64);        // lane ha holds (j=0, hw=ha)
    float4 bv = *(const float4*)(b1 + ch0);
    float o0 = a0 / sden + bv.x;
    float o1 = a1 / sden + bv.y;
    float o2 = a2 / sden + bv.z;
    float o3 = a3 / sden + bv.w;
    o0 = o0 > 0.f ? o0 : expm1f(o0);          // fused bias + ELU
    o1 = o1 > 0.f ? o1 : expm1f(o1);
    o2 = o2 > 0.f ? o2 : expm1f(o2);
    o3 = o3 > 0.f ? o3 : expm1f(o3);
    float4 w01 = *(const float4*)(W2 + ch0 * 2);
    float4 w23 = *(const float4*)(W2 + ch0 * 2 + 4);
    float p0 = o0 * w01.x + o1 * w01.z + o2 * w23.x + o3 * w23.z;
    float p1 = o0 * w01.y + o1 * w01.w + o2 * w23.y + o3 * w23.w;
    #pragma unroll
    for (int off = 8; off > 0; off >>= 1) {
        p0 += __shfl_xor(p0, off, 64);
        p1 += __shfl_xor(p1, off, 64);
    }
    if (lane == 0) {
        float es2v = (p0 * as2[0] + p1 * as2[1]) * LOG2E;
        float ed2v = (p0 * ad2[0] + p1 * ad2[1]) * LOG2E;
        node2[wid] = make_float4(es2v, p0, p1, ed2v);
    }
}

// ---------------- Layer 2 aggregation + bias + log_softmax ----------------

__global__ void k_agg2(const float4* __restrict__ node2, const int* __restrict__ rowptr,
                       const int* __restrict__ degv, const int* __restrict__ csr,
                       const float* __restrict__ b2, float* __restrict__ out, int n) {
    int lane = threadIdx.x & 63;
    int wid = ((blockIdx.x * blockDim.x + threadIdx.x) >> 6) * 4 + (lane >> 4);
    if (wid >= n) return;
    int l16 = lane & 15;
    int start = rowptr[wid];
    int cnt = degv[wid];
    float edv = ((const float*)node2)[wid * 4 + 3];
    float sw = 0.f, a0 = 0.f, a1 = 0.f;
    for (int i = l16; i < cnt; i += 16) {
        int s = __builtin_nontemporal_load(csr + start + i);
        float4 t = node2[s];
        float val = t.x + edv;
        val = fmaxf(val, NEG * val);
        float w = exp2f(val);
        sw += w;
        a0 += w * t.y;
        a1 += w * t.z;
    }
    #pragma unroll
    for (int off = 8; off > 0; off >>= 1) {
        sw += __shfl_xor(sw, off, 16);
        a0 += __shfl_xor(a0, off, 16);
        a1 += __shfl_xor(a1, off, 16);
    }
    if (l16 == 0) {
        float z0 = a0 / sw + b2[0];
        float z1 = a1 / sw + b2[1];
        float mz = fmaxf(z0, z1);
        float lse = mz + logf(__expf(z0 - mz) + __expf(z1 - mz));
        out[wid * NCLS + 0] = z0 - lse;
        out[wid * NCLS + 1] = z1 - lse;
    }
}

// ---------------- launch ----------------

extern "C" void kernel_launch(void* const* d_in, const int* in_sizes, int n_in,
                              void* d_out, int out_size, void* d_ws, size_t ws_size,
                              hipStream_t stream) {
    const float* x   = (const float*)d_in[0];
    const int*   ei  = (const int*)d_in[1];
    const float* W1  = (const float*)d_in[2];
    const float* as1 = (const float*)d_in[3];
    const float* ad1 = (const float*)d_in[4];
    const float* b1  = (const float*)d_in[5];
    const float* W2  = (const float*)d_in[6];
    const float* as2 = (const float*)d_in[7];
    const float* ad2 = (const float*)d_in[8];
    const float* b2  = (const float*)d_in[9];
    float* out = (float*)d_out;

    const int n = in_sizes[0] / FIN;     // 50000
    const int e = in_sizes[1] / 2;       // 1600000
    const int nbin = (e + BCHUNK - 1) / BCHUNK;   // 391 (real edges only)

    char* ws = (char*)d_ws;
    size_t off = 0;
    auto alloc = [&](size_t bytes) -> void* {
        void* p = ws + off;
        off += (bytes + 255) & ~(size_t)255;
        return p;
    };
    __hip_bfloat16* h1b  = (__hip_bfloat16*)alloc((size_t)n * HC * 2);
    __hip_bfloat16* es1b = (__hip_bfloat16*)alloc((size_t)n * NHEAD * 2);
    int* pairs   = (int*)alloc((size_t)NBKT * nbin * SLOT * 4);   // 25.6 MB deterministic slots
    int* cnt     = (int*)alloc((size_t)nbin * NBKT * 4);          // per-(block,bucket) counts
    int* csr     = (int*)alloc((size_t)NBKT * CAP * 4);           // 8 MB, padded layout
    float* ed1   = (float*)alloc((size_t)n * NHEAD * 4);
    float4* node2 = (float4*)alloc((size_t)n * 16);
    int* rowptr  = (int*)alloc((size_t)n * 4);
    int* degv    = (int*)alloc((size_t)n * 4);

    // fused: binning (391 blocks, no global atomics) || layer-1 GEMM (1024 blocks)
    k_bin_h1<<<nbin + 1024, 256, 0, stream>>>(ei, cnt, pairs, e, nbin,
                                              x, W1, as1, ad1, h1b, es1b, ed1, n);
    k_bucket_csr<<<NBKT, 256, 0, stream>>>(pairs, cnt, rowptr, degv, csr, n, nbin);
    k_agg1<<<(n * 64 + 255) / 256, 256, 0, stream>>>(h1b, es1b, ed1, rowptr, degv, csr,
                                                     b1, W2, as2, ad2, node2, n);
    k_agg2<<<(n * 16 + 255) / 256, 256, 0, stream>>>(node2, rowptr, degv, csr, b2, out, n);
}

// Round 22
// 103.920 us; speedup vs baseline: 1.1567x; 1.1567x over previous
//
#include <hip/hip_runtime.h>
#include <hip/hip_bf16.h>
#include <math.h>

#define NN 50000
#define FIN 48
#define HC 64   // 8 heads x 8 ch
#define NHEAD 8
#define NCH 8
#define NCLS 2
#define NEG 0.2f
#define LOG2E 1.44269504f

#define NPB 98                         // nodes per bucket
#define NBKT 512                       // buckets (NPB*NBKT >= NN)
#define CAP 4096                       // fixed slot capacity (E[fill]=3225, +15 sigma)
#define BCHUNK 4096                    // edges per binning workgroup

__global__ void k_zero(int* p, int n) {
    int i = blockIdx.x * blockDim.x + threadIdx.x;
    if (i < n) p[i] = 0;
}

// ---------------- fused: edge binning (blocks 0..nbin-1)  ||  layer-1 GEMM (rest) ----------------
// binning: two-pass; int4 vector loads (one s_waitcnt covers 4 edges; self-loop
// quads need no loads). Reserve via global atomics (R19-proven).

__global__ void k_bin_h1(const int* __restrict__ ei, int* __restrict__ bcur,
                         int* __restrict__ pairs, int e, int tot, int nbin,
                         const float* __restrict__ x, const float* __restrict__ W1,
                         const float* __restrict__ as1, const float* __restrict__ ad1,
                         __hip_bfloat16* __restrict__ h1b, __hip_bfloat16* __restrict__ es1b,
                         float* __restrict__ ed1, int n) {
    __shared__ int hist[NBKT];
    __shared__ int gbase[NBKT];
    __shared__ float xs[16][FIN];
    int t = threadIdx.x;
    if ((int)blockIdx.x < nbin) {
        hist[t] = 0; hist[t + 256] = 0;
        __syncthreads();
        int base = blockIdx.x * BCHUNK;
        int end = min(base + BCHUNK, tot);
        int nitems = end - base;
        int nq = nitems >> 2;
        // ---- pass 1: histogram, int4 loads ----
        for (int q = t; q < nq; q += 256) {
            int i0 = base + (q << 2);
            int d0, d1, d2, d3;
            if (i0 + 3 < e) {
                int4 dv = *(const int4*)(ei + e + i0);
                d0 = dv.x; d1 = dv.y; d2 = dv.z; d3 = dv.w;
            } else if (i0 >= e) {
                d0 = i0 - e; d1 = d0 + 1; d2 = d0 + 2; d3 = d0 + 3;
            } else {
                d0 = (i0     < e) ? ei[e + i0]     : i0 - e;
                d1 = (i0 + 1 < e) ? ei[e + i0 + 1] : i0 + 1 - e;
                d2 = (i0 + 2 < e) ? ei[e + i0 + 2] : i0 + 2 - e;
                d3 = (i0 + 3 < e) ? ei[e + i0 + 3] : i0 + 3 - e;
            }
            atomicAdd(&hist[d0 / NPB], 1);
            atomicAdd(&hist[d1 / NPB], 1);
            atomicAdd(&hist[d2 / NPB], 1);
            atomicAdd(&hist[d3 / NPB], 1);
        }
        for (int i = base + (nq << 2) + t; i < end; i += 256) {
            int d = (i < e) ? ei[e + i] : (i - e);
            atomicAdd(&hist[d / NPB], 1);
        }
        __syncthreads();
        // reserve global ranges
        for (int u = t; u < NBKT; u += 256) {
            int h = hist[u];
            gbase[u] = h ? atomicAdd(&bcur[u], h) : 0;
        }
        __syncthreads();
        hist[t] = 0; hist[t + 256] = 0;
        __syncthreads();
        // ---- pass 2: re-read (L2-hot), int4 loads, direct write ----
        for (int q = t; q < nq; q += 256) {
            int i0 = base + (q << 2);
            int s0, d0, s1, d1, s2, d2, s3, d3;
            if (i0 + 3 < e) {
                int4 sv = *(const int4*)(ei + i0);
                int4 dv = *(const int4*)(ei + e + i0);
                s0 = sv.x; s1 = sv.y; s2 = sv.z; s3 = sv.w;
                d0 = dv.x; d1 = dv.y; d2 = dv.z; d3 = dv.w;
            } else if (i0 >= e) {
                s0 = d0 = i0 - e; s1 = d1 = d0 + 1; s2 = d2 = d0 + 2; s3 = d3 = d0 + 3;
            } else {
                if (i0     < e) { s0 = ei[i0];     d0 = ei[e + i0];     } else { s0 = d0 = i0 - e; }
                if (i0 + 1 < e) { s1 = ei[i0 + 1]; d1 = ei[e + i0 + 1]; } else { s1 = d1 = i0 + 1 - e; }
                if (i0 + 2 < e) { s2 = ei[i0 + 2]; d2 = ei[e + i0 + 2]; } else { s2 = d2 = i0 + 2 - e; }
                if (i0 + 3 < e) { s3 = ei[i0 + 3]; d3 = ei[e + i0 + 3]; } else { s3 = d3 = i0 + 3 - e; }
            }
            int b0 = d0 / NPB, b1 = d1 / NPB, b2 = d2 / NPB, b3 = d3 / NPB;
            int p0 = gbase[b0] + atomicAdd(&hist[b0], 1);
            int p1 = gbase[b1] + atomicAdd(&hist[b1], 1);
            int p2 = gbase[b2] + atomicAdd(&hist[b2], 1);
            int p3 = gbase[b3] + atomicAdd(&hist[b3], 1);
            if (p0 < CAP) pairs[b0 * CAP + p0] = ((d0 - b0 * NPB) << 16) | s0;
            if (p1 < CAP) pairs[b1 * CAP + p1] = ((d1 - b1 * NPB) << 16) | s1;
            if (p2 < CAP) pairs[b2 * CAP + p2] = ((d2 - b2 * NPB) << 16) | s2;
            if (p3 < CAP) pairs[b3 * CAP + p3] = ((d3 - b3 * NPB) << 16) | s3;
        }
        for (int i = base + (nq << 2) + t; i < end; i += 256) {
            int s, d;
            if (i < e) { s = ei[i]; d = ei[e + i]; }
            else       { s = d = i - e; }
            int b = d / NPB;
            int p = gbase[b] + atomicAdd(&hist[b], 1);
            if (p < CAP) pairs[b * CAP + p] = ((d - b * NPB) << 16) | s;
        }
    } else {
        // ---- layer-1: register-tiled GEMM (unchanged) ----
        int j = t & 63, row = t >> 6;
        float wreg[FIN];
        #pragma unroll
        for (int k = 0; k < FIN; ++k) wreg[k] = W1[k * HC + j];
        float asl = as1[j] * LOG2E, adl = ad1[j] * LOG2E;
        int hh = j >> 3, c = j & 7;
        int ngroups = (n + 15) >> 4;
        int GB = gridDim.x - nbin;
        for (int g = blockIdx.x - nbin; g < ngroups; g += GB) {
            int nb = g * 16;
            __syncthreads();
            for (int i = t; i < 16 * FIN; i += 256) {
                int l = i / FIN, k = i % FIN;
                int nd = nb + l;
                xs[l][k] = (nd < n) ? x[nd * FIN + k] : 0.f;
            }
            __syncthreads();
            #pragma unroll
            for (int m = 0; m < 4; ++m) {
                int l = (row << 2) + m;
                float acc = 0.f;
                #pragma unroll
                for (int k = 0; k < FIN; ++k) acc += xs[l][k] * wreg[k];
                int nd = nb + l;
                if (nd < n) h1b[nd * HC + j] = __float2bfloat16(acc);
                float es = acc * asl, ed = acc * adl;
                es += __shfl_xor(es, 1, 64); es += __shfl_xor(es, 2, 64); es += __shfl_xor(es, 4, 64);
                ed += __shfl_xor(ed, 1, 64); ed += __shfl_xor(ed, 2, 64); ed += __shfl_xor(ed, 4, 64);
                if (nd < n) {
                    if (c == 0) es1b[nd * NHEAD + hh] = __float2bfloat16(es);
                    if (c == 1) ed1[nd * NHEAD + hh] = ed;
                }
            }
        }
    }
}

// ---------------- per-bucket CSR: two-pass, uint4 loads on contiguous pairs ----------------

__global__ void k_bucket_csr(const int* __restrict__ pairs, const int* __restrict__ bcur,
                             int* __restrict__ rowptr, int* __restrict__ degv,
                             int* __restrict__ csr, int n) {
    __shared__ int hist[256];
    int b = blockIdx.x, t = threadIdx.x;
    int lo = b * NPB;
    int nn = min(NPB, n - lo);
    if (nn <= 0) return;
    int base = b * CAP;
    int cnt = min(bcur[b], CAP);
    int nq = cnt >> 2;
    hist[t] = 0;
    __syncthreads();
    // pass 1: degree histogram, int4 loads
    for (int q = t; q < nq; q += 256) {
        int4 p = *(const int4*)(pairs + base + (q << 2));
        atomicAdd(&hist[p.x >> 16], 1);
        atomicAdd(&hist[p.y >> 16], 1);
        atomicAdd(&hist[p.z >> 16], 1);
        atomicAdd(&hist[p.w >> 16], 1);
    }
    for (int i = (nq << 2) + t; i < cnt; i += 256) {
        atomicAdd(&hist[pairs[base + i] >> 16], 1);
    }
    __syncthreads();
    int v = hist[t];
    for (int off = 1; off < 256; off <<= 1) {           // inclusive scan
        int y = (t >= off) ? hist[t - off] : 0;
        __syncthreads();
        hist[t] += y;
        __syncthreads();
    }
    int excl = hist[t] - v;
    if (t < nn) { rowptr[lo + t] = base + excl; degv[lo + t] = v; }
    __syncthreads();
    hist[t] = excl;                                      // exclusive offsets as cursors
    __syncthreads();
    // pass 2: scatter within bucket, int4 loads
    for (int q = t; q < nq; q += 256) {
        int4 p = *(const int4*)(pairs + base + (q << 2));
        int q0 = atomicAdd(&hist[p.x >> 16], 1);
        int q1 = atomicAdd(&hist[p.y >> 16], 1);
        int q2 = atomicAdd(&hist[p.z >> 16], 1);
        int q3 = atomicAdd(&hist[p.w >> 16], 1);
        csr[base + q0] = p.x & 0xFFFF;
        csr[base + q1] = p.y & 0xFFFF;
        csr[base + q2] = p.z & 0xFFFF;
        csr[base + q3] = p.w & 0xFFFF;
    }
    for (int i = (nq << 2) + t; i < cnt; i += 256) {
        int p = pairs[base + i];
        int pos = atomicAdd(&hist[p >> 16], 1);
        csr[base + pos] = p & 0xFFFF;
    }
}

// ---------------- Layer 1 aggregation + fused layer-2 linear ----------------
// wave per dst node; csr row preloaded into rv register; no load->address deps in loop.

__global__ void k_agg1(const __hip_bfloat16* __restrict__ h1b, const __hip_bfloat16* __restrict__ es1b,
                       const float* __restrict__ ed1, const int* __restrict__ rowptr,
                       const int* __restrict__ degv, const int* __restrict__ csr,
                       const float* __restrict__ b1,
                       const float* __restrict__ W2, const float* __restrict__ as2,
                       const float* __restrict__ ad2, float4* __restrict__ node2, int n) {
    int wid = (blockIdx.x * blockDim.x + threadIdx.x) >> 6;
    if (wid >= n) return;
    int lane = threadIdx.x & 63;
    int j  = lane >> 3;                      // weight: edge slot (0..7)
    int hw = lane & 7;                       // weight: head
    int e4 = lane >> 4;                      // accum: edge sub-slot (0..3)
    int r  = lane & 15;
    int ha = r >> 1;                         // accum: head
    int ch0 = (ha << 3) + ((r & 1) << 2);    // first of this lane's 4 channels
    int wbase = (e4 << 3) + ha;              // lane with w(edge e4, head ha); +32 -> edge e4+4
    int start = rowptr[wid];
    int cnt = degv[wid];
    float edv = ed1[wid * NHEAD + hw];
    float sumw = 0.f;
    float a0 = 0.f, a1 = 0.f, a2 = 0.f, a3 = 0.f;
    int nbatch = cnt >> 3;

    // preload first 64 src ids of the row (cnt >= 1 always: self-loop)
    int rv = csr[start + min(lane, cnt - 1)];

    int sl; float ev; uint2 va, vb;
    if (nbatch > 0) {
        sl = __shfl(rv, j, 64);
        ev = __bfloat162float(es1b[sl * NHEAD + hw]);
        int su0 = __shfl(sl, e4 << 3, 64);
        int su1 = __shfl(sl, (4 + e4) << 3, 64);
        va = *(const uint2*)(h1b + su0 * HC + ch0);
        vb = *(const uint2*)(h1b + su1 * HC + ch0);
        for (int b = 1; b < nbatch; ++b) {
            int sl_n;
            if (b < 8) sl_n = __shfl(rv, (b << 3) + j, 64);   // register-sourced
            else       sl_n = csr[start + (b << 3) + j];      // deg>64: rare fallback
            float ev_n = __bfloat162float(es1b[sl_n * NHEAD + hw]);
            int su0n = __shfl(sl_n, e4 << 3, 64);
            int su1n = __shfl(sl_n, (4 + e4) << 3, 64);
            uint2 va_n = *(const uint2*)(h1b + su0n * HC + ch0);
            uint2 vb_n = *(const uint2*)(h1b + su1n * HC + ch0);
            // consume previous batch
            float tt = ev + edv;
            tt = fmaxf(tt, NEG * tt);
            float w = exp2f(tt);
            sumw += w;
            float wj0 = __shfl(w, wbase, 64);
            float wj1 = __shfl(w, wbase + 32, 64);
            a0 += wj0 * __uint_as_float(va.x << 16);
            a1 += wj0 * __uint_as_float(va.x & 0xffff0000u);
            a2 += wj0 * __uint_as_float(va.y << 16);
            a3 += wj0 * __uint_as_float(va.y & 0xffff0000u);
            a0 += wj1 * __uint_as_float(vb.x << 16);
            a1 += wj1 * __uint_as_float(vb.x & 0xffff0000u);
            a2 += wj1 * __uint_as_float(vb.y << 16);
            a3 += wj1 * __uint_as_float(vb.y & 0xffff0000u);
            sl = sl_n; ev = ev_n; va = va_n; vb = vb_n;
        }
        float tt = ev + edv;
        tt = fmaxf(tt, NEG * tt);
        float w = exp2f(tt);
        sumw += w;
        float wj0 = __shfl(w, wbase, 64);
        float wj1 = __shfl(w, wbase + 32, 64);
        a0 += wj0 * __uint_as_float(va.x << 16);
        a1 += wj0 * __uint_as_float(va.x & 0xffff0000u);
        a2 += wj0 * __uint_as_float(va.y << 16);
        a3 += wj0 * __uint_as_float(va.y & 0xffff0000u);
        a0 += wj1 * __uint_as_float(vb.x << 16);
        a1 += wj1 * __uint_as_float(vb.x & 0xffff0000u);
        a2 += wj1 * __uint_as_float(vb.y << 16);
        a3 += wj1 * __uint_as_float(vb.y & 0xffff0000u);
    }
    int i = nbatch << 3;
    if (i < cnt) {                            // tail batch (clamped)
        int idx = min(i + j, cnt - 1);
        int slt = (cnt <= 64) ? __shfl(rv, idx, 64) : csr[start + idx];
        float evt = __bfloat162float(es1b[slt * NHEAD + hw]) + edv;
        evt = fmaxf(evt, NEG * evt);
        float w = (i + j < cnt) ? exp2f(evt) : 0.f;
        sumw += w;
        #pragma unroll
        for (int it = 0; it < 2; ++it) {
            int su   = __shfl(slt, ((it << 2) + e4) << 3, 64);
            float wj = __shfl(w, wbase + (it << 5), 64);
            uint2 v = *(const uint2*)(h1b + su * HC + ch0);
            a0 += wj * __uint_as_float(v.x << 16);
            a1 += wj * __uint_as_float(v.x & 0xffff0000u);
            a2 += wj * __uint_as_float(v.y << 16);
            a3 += wj * __uint_as_float(v.y & 0xffff0000u);
        }
    }
    // denominator: sum over edge slots j (lane stride 8) for fixed head hw
    sumw += __shfl_xor(sumw, 8, 64);
    sumw += __shfl_xor(sumw, 16, 64);
    sumw += __shfl_xor(sumw, 32, 64);
    // accumulator: sum the 4 edge sub-groups (lanes with same r)
    a0 += __shfl_xor(a0, 16, 64); a0 += __shfl_xor(a0, 32, 64);
    a1 += __shfl_xor(a1, 16, 64); a1 += __shfl_xor(a1, 32, 64);
    a2 += __shfl_xor(a2, 16, 64); a2 += __shfl_xor(a2, 32, 64);
    a3 += __shfl_xor(a3, 16, 64); a3 += __shfl_xor(a3, 32, 64);
    float sden = __shfl(sumw, ha, 64);        // lane ha holds (j=0, hw=ha)
    float4 bv = *(const float4*)(b1 + ch0);
    float o0 = a0 / sden + bv.x;
    float o1 = a1 / sden + bv.y;
    float o2 = a2 / sden + bv.z;
    float o3 = a3 / sden + bv.w;
    o0 = o0 > 0.f ? o0 : expm1f(o0);          // fused bias + ELU
    o1 = o1 > 0.f ? o1 : expm1f(o1);
    o2 = o2 > 0.f ? o2 : expm1f(o2);
    o3 = o3 > 0.f ? o3 : expm1f(o3);
    float4 w01 = *(const float4*)(W2 + ch0 * 2);
    float4 w23 = *(const float4*)(W2 + ch0 * 2 + 4);
    float p0 = o0 * w01.x + o1 * w01.z + o2 * w23.x + o3 * w23.z;
    float p1 = o0 * w01.y + o1 * w01.w + o2 * w23.y + o3 * w23.w;
    #pragma unroll
    for (int off = 8; off > 0; off >>= 1) {
        p0 += __shfl_xor(p0, off, 64);
        p1 += __shfl_xor(p1, off, 64);
    }
    if (lane == 0) {
        float es2v = (p0 * as2[0] + p1 * as2[1]) * LOG2E;
        float ed2v = (p0 * ad2[0] + p1 * ad2[1]) * LOG2E;
        node2[wid] = make_float4(es2v, p0, p1, ed2v);
    }
}

// ---------------- Layer 2 aggregation + bias + log_softmax ----------------

__global__ void k_agg2(const float4* __restrict__ node2, const int* __restrict__ rowptr,
                       const int* __restrict__ degv, const int* __restrict__ csr,
                       const float* __restrict__ b2, float* __restrict__ out, int n) {
    int lane = threadIdx.x & 63;
    int wid = ((blockIdx.x * blockDim.x + threadIdx.x) >> 6) * 4 + (lane >> 4);
    if (wid >= n) return;
    int l16 = lane & 15;
    int start = rowptr[wid];
    int cnt = degv[wid];
    float edv = ((const float*)node2)[wid * 4 + 3];
    float sw = 0.f, a0 = 0.f, a1 = 0.f;
    for (int i = l16; i < cnt; i += 16) {
        int s = __builtin_nontemporal_load(csr + start + i);
        float4 t = node2[s];
        float val = t.x + edv;
        val = fmaxf(val, NEG * val);
        float w = exp2f(val);
        sw += w;
        a0 += w * t.y;
        a1 += w * t.z;
    }
    #pragma unroll
    for (int off = 8; off > 0; off >>= 1) {
        sw += __shfl_xor(sw, off, 16);
        a0 += __shfl_xor(a0, off, 16);
        a1 += __shfl_xor(a1, off, 16);
    }
    if (l16 == 0) {
        float z0 = a0 / sw + b2[0];
        float z1 = a1 / sw + b2[1];
        float mz = fmaxf(z0, z1);
        float lse = mz + logf(__expf(z0 - mz) + __expf(z1 - mz));
        out[wid * NCLS + 0] = z0 - lse;
        out[wid * NCLS + 1] = z1 - lse;
    }
}

// ---------------- launch ----------------

extern "C" void kernel_launch(void* const* d_in, const int* in_sizes, int n_in,
                              void* d_out, int out_size, void* d_ws, size_t ws_size,
                              hipStream_t stream) {
    const float* x   = (const float*)d_in[0];
    const int*   ei  = (const int*)d_in[1];
    const float* W1  = (const float*)d_in[2];
    const float* as1 = (const float*)d_in[3];
    const float* ad1 = (const float*)d_in[4];
    const float* b1  = (const float*)d_in[5];
    const float* W2  = (const float*)d_in[6];
    const float* as2 = (const float*)d_in[7];
    const float* ad2 = (const float*)d_in[8];
    const float* b2  = (const float*)d_in[9];
    float* out = (float*)d_out;

    const int n = in_sizes[0] / FIN;     // 50000
    const int e = in_sizes[1] / 2;       // 1600000
    const int tot = e + n;               // edges incl. self-loops

    char* ws = (char*)d_ws;
    size_t off = 0;
    auto alloc = [&](size_t bytes) -> void* {
        void* p = ws + off;
        off += (bytes + 255) & ~(size_t)255;
        return p;
    };
    __hip_bfloat16* h1b  = (__hip_bfloat16*)alloc((size_t)n * HC * 2);
    __hip_bfloat16* es1b = (__hip_bfloat16*)alloc((size_t)n * NHEAD * 2);
    int* pairs   = (int*)alloc((size_t)NBKT * CAP * 4);     // 8 MB, fixed slots
    int* csr     = (int*)alloc((size_t)NBKT * CAP * 4);     // 8 MB, padded layout
    float* ed1   = (float*)alloc((size_t)n * NHEAD * 4);
    float4* node2 = (float4*)alloc((size_t)n * 16);
    int* rowptr  = (int*)alloc((size_t)n * 4);
    int* degv    = (int*)alloc((size_t)n * 4);
    int* bcur    = (int*)alloc((size_t)NBKT * 4);

    const int nbin = (tot + BCHUNK - 1) / BCHUNK;   // 403

    k_zero<<<(NBKT + 255) / 256, 256, 0, stream>>>(bcur, NBKT);
    // fused: binning (403 blocks) || layer-1 register-tiled GEMM (1024 blocks)
    k_bin_h1<<<nbin + 1024, 256, 0, stream>>>(ei, bcur, pairs, e, tot, nbin,
                                              x, W1, as1, ad1, h1b, es1b, ed1, n);
    k_bucket_csr<<<NBKT, 256, 0, stream>>>(pairs, bcur, rowptr, degv, csr, n);
    k_agg1<<<(n * 64 + 255) / 256, 256, 0, stream>>>(h1b, es1b, ed1, rowptr, degv, csr,
                                                     b1, W2, as2, ad2, node2, n);
    k_agg2<<<(n * 16 + 255) / 256, 256, 0, stream>>>(node2, rowptr, degv, csr, b2, out, n);
}